// Round 1
// baseline (4460.858 us; speedup 1.0000x reference)
//
#include <hip/hip_runtime.h>
#include <math.h>

#define HH 32
#define WW 64
#define HW 2048

// x0 = (data - 3.5) * mask   (batch collapsed to 1: all 3 copies identical)
__global__ void prep_kernel(const float* __restrict__ data,
                            const float* __restrict__ mask,
                            float* __restrict__ x0) {
    int i = blockIdx.x * 256 + threadIdx.x;
    if (i < 64 * HW) x0[i] = (data[i] - 3.5f) * mask[i];
}

// Masked 5x5 SAME conv, NCHW batch-1.
// Mask rule: tap (ky,kx) allowed iff ky+kx <= lim, lim = lim_base - (ci/cpg_in - co/cpg_out).
//   lim_base = 3 for strict (<0), 4 for non-strict (<=0).
// Block: 256 threads; blockIdx.x = co tile (32 ch), blockIdx.y = output row h.
// Thread t: co = co0 + (t>>3), outputs w = (t&7)*8 .. +7.
// OUT = [RES +] (relu?)(conv + bias)
__global__ __launch_bounds__(256) void conv_kernel(
    const float* __restrict__ IN, const float* __restrict__ Wt,
    const float* __restrict__ Bs, const float* __restrict__ RES,
    float* __restrict__ OUT, int Cin, int Cout,
    int cpg_out, int cpg_in, int lim_base, int do_relu)
{
    __shared__ float lds[16 * 5 * 72];   // [ci_local][row 0..4][col+2 halo, padded to 72]
    const int co0 = blockIdx.x * 32;
    const int h   = blockIdx.y;
    const int t   = threadIdx.x;
    const int co  = co0 + (t >> 3);
    const int w0  = (t & 7) * 8;
    const int g_out = co / cpg_out;

    float acc[8];
#pragma unroll
    for (int i = 0; i < 8; i++) acc[i] = 0.f;

    // highest ci with any unmasked tap for this co-tile
    int maxg = (co0 + 31) / cpg_out;
    int ci_max = (maxg + lim_base) * cpg_in + (cpg_in - 1);
    if (ci_max > Cin - 1) ci_max = Cin - 1;

    for (int ci0 = 0; ci0 <= ci_max; ci0 += 16) {
        // ---- stage 16 input channels x 5 rows (h-2..h+2) with col halo ----
        for (int idx = t; idx < 16 * 5 * 72; idx += 256) {
            int ci_l = idx / (5 * 72);
            int rem  = idx % (5 * 72);
            int r    = rem / 72;
            int c    = rem % 72;
            int ih = h - 2 + r;
            int ic = c - 2;
            float v = 0.f;
            if (ih >= 0 && ih < HH && ic >= 0 && ic < WW)
                v = IN[(size_t)(ci0 + ci_l) * HW + ih * WW + ic];
            lds[idx] = v;
        }
        __syncthreads();

#pragma unroll 1
        for (int ci_l = 0; ci_l < 16; ci_l++) {
            int ci  = ci0 + ci_l;
            int lim = lim_base - (ci / cpg_in - g_out);
            if (lim < 0) continue;                       // fully masked
            const float* wp = Wt + ((size_t)co * Cin + ci) * 25;
            const float* lp = lds + ci_l * 5 * 72 + w0;
            if (lim >= 8) {
                // fully unmasked: 25 taps, unrolled
#pragma unroll
                for (int ky = 0; ky < 5; ky++) {
                    float xv[12];
#pragma unroll
                    for (int j = 0; j < 12; j++) xv[j] = lp[ky * 72 + j];
#pragma unroll
                    for (int kx = 0; kx < 5; kx++) {
                        float wv = wp[ky * 5 + kx];
#pragma unroll
                        for (int wi = 0; wi < 8; wi++) acc[wi] += wv * xv[wi + kx];
                    }
                }
            } else {
                // boundary group: ky+kx <= lim
                int kym = lim < 4 ? lim : 4;
                for (int ky = 0; ky <= kym; ky++) {
                    float xv[12];
#pragma unroll
                    for (int j = 0; j < 12; j++) xv[j] = lp[ky * 72 + j];
                    int kxm = lim - ky; if (kxm > 4) kxm = 4;
                    for (int kx = 0; kx <= kxm; kx++) {
                        float wv = wp[ky * 5 + kx];
#pragma unroll
                        for (int wi = 0; wi < 8; wi++) acc[wi] += wv * xv[wi + kx];
                    }
                }
            }
        }
        __syncthreads();
    }

    float b = Bs[co];
    size_t obase = (size_t)co * HW + (size_t)h * WW + w0;
#pragma unroll
    for (int wi = 0; wi < 8; wi++) {
        float y = acc[wi] + b;
        if (do_relu) y = fmaxf(y, 0.f);
        if (RES) y += RES[obase + wi];
        OUT[obase + wi] = y;
    }
}

// table[g,h,w,k] = 65536 * 0.5*(1+erf((k-3 - mu)/(sig*sqrt2)))
// (softmax over 3 identical logits == 1/3 each; sum of identical cdfs == cdf)
__global__ void final_kernel(const float* __restrict__ Y, float* __restrict__ OUT) {
    int i = blockIdx.x * 256 + threadIdx.x;   // over 64*2048 pixels
    if (i >= 64 * HW) return;
    int g = i / HW;
    int p = i % HW;
    float mu = Y[(size_t)(g * 3 + 1) * HW + p];
    float s  = Y[(size_t)(g * 3 + 2) * HW + p];
    // stable softplus
    float sp  = fmaxf(s, 0.f) + log1pf(expf(-fabsf(s)));
    float sig = sp + 1e-6f;
    float inv = 1.f / (sig * 1.41421356237f);
#pragma unroll
    for (int k = 0; k < 8; k++) {
        float z = ((float)k - 3.0f - mu) * inv;
        OUT[(size_t)i * 8 + k] = 32768.f * (1.f + erff(z));
    }
}

extern "C" void kernel_launch(void* const* d_in, const int* in_sizes, int n_in,
                              void* d_out, int out_size, void* d_ws, size_t ws_size,
                              hipStream_t stream) {
    const float* data  = (const float*)d_in[0];
    const float* mask  = (const float*)d_in[1];
    const float* w_in  = (const float*)d_in[2];
    const float* b_in  = (const float*)d_in[3];
    const float* w_hid = (const float*)d_in[4];
    const float* b_hid = (const float*)d_in[5];
    const float* w_out = (const float*)d_in[6];
    const float* b_out = (const float*)d_in[7];
    float* out = (float*)d_out;

    float* ws = (float*)d_ws;
    float* X0 = ws;                  // 64*2048
    float* A  = X0 + 64 * HW;        // 256*2048
    float* B  = A + 256 * HW;        // 256*2048
    float* C  = B + 256 * HW;        // 256*2048
    float* Y  = C + 256 * HW;        // 192*2048

    prep_kernel<<<512, 256, 0, stream>>>(data, mask, X0);

    dim3 blk(256);
    // input conv: 64 -> 256, strict mask (lim_base=3), cpg_in=1
    conv_kernel<<<dim3(8, 32), blk, 0, stream>>>(X0, w_in, b_in, nullptr, A,
                                                 64, 256, 4, 1, 3, 1);
    float* x = A;
    float* other = C;
    for (int i = 0; i < 5; i++) {
        const float* w1 = w_hid + (size_t)(2 * i) * 256 * 256 * 25;
        const float* w2 = w_hid + (size_t)(2 * i + 1) * 256 * 256 * 25;
        const float* bb1 = b_hid + (size_t)(2 * i) * 256;
        const float* bb2 = b_hid + (size_t)(2 * i + 1) * 256;
        conv_kernel<<<dim3(8, 32), blk, 0, stream>>>(x, w1, bb1, nullptr, B,
                                                     256, 256, 4, 4, 4, 1);
        conv_kernel<<<dim3(8, 32), blk, 0, stream>>>(B, w2, bb2, x, other,
                                                     256, 256, 4, 4, 4, 1);
        float* tmp = x; x = other; other = tmp;
    }
    // output conv: 256 -> 192, non-strict mask, no relu
    conv_kernel<<<dim3(6, 32), blk, 0, stream>>>(x, w_out, b_out, nullptr, Y,
                                                 256, 192, 3, 4, 4, 0);

    final_kernel<<<512, 256, 0, stream>>>(Y, out);
}

// Round 5
// 1194.267 us; speedup vs baseline: 3.7352x; 3.7352x over previous
//
#include <hip/hip_runtime.h>
#include <math.h>

typedef _Float16 f16;
typedef _Float16 f16x8 __attribute__((ext_vector_type(8)));
typedef float f32x4 __attribute__((ext_vector_type(4)));

#define HH 32
#define WW 64
#define NPX 2048   // 32*64 pixels
// lo-planes are stored pre-scaled by 2^11 so they stay in fp16 NORMAL range
// (raw residuals ~2^-11*|x| would be denormal and may be flushed by MFMA).
#define LOSCALE 2048.0f
#define INV_LOSCALE 4.8828125e-4f   // 1/2048, exact

// ---- prep: X0h[px][ci] = (data-3.5)*mask (exact in fp16: multiples of 0.5), lo=0
__global__ void prep_kernel(const float* __restrict__ data,
                            const float* __restrict__ mask,
                            f16* __restrict__ X0, int plane) {
    int idx = blockIdx.x * 256 + threadIdx.x;      // px*64 + ci
    if (idx >= NPX * 64) return;
    int px = idx >> 6, ci = idx & 63;
    float v = (data[ci * NPX + px] - 3.5f) * mask[ci * NPX + px];
    X0[idx] = (f16)v;
    X0[plane + idx] = (f16)0.f;
}

// ---- repack: WP[0][tap][co_p][ci] = fp16(w_masked); WP[1][...] = fp16((w-hi)*2048)
// is_out: co_p = g*2+c  ->  orig co = g*3+1+c (mu,sig only; logits provably unused:
// the 3 batch copies are identical so softmax weights are exactly 1/3 each)
__global__ void repack_kernel(const float* __restrict__ W, f16* __restrict__ WP,
                              int cin_log2, int coutp_log2,
                              int cpg_in_log2, int limb, int is_out) {
    int idx = blockIdx.x * 256 + threadIdx.x;
    int Cin = 1 << cin_log2;
    int plane = 25 << (cin_log2 + coutp_log2);
    int ci = idx & (Cin - 1);
    int rest = idx >> cin_log2;
    int co_p = rest & ((1 << coutp_log2) - 1);
    int tap = rest >> coutp_log2;
    if (tap >= 25) return;
    int ky = tap / 5, kx = tap - 5 * ky;
    int co_orig, g_out;
    if (is_out) { g_out = co_p >> 1; co_orig = 3 * g_out + 1 + (co_p & 1); }
    else        { g_out = co_p >> 2; co_orig = co_p; }
    int g_in = ci >> cpg_in_log2;
    float v = 0.f;
    if (ky + kx <= limb + g_out - g_in)
        v = W[(co_orig * Cin + ci) * 25 + tap];
    f16 vh = (f16)v;
    WP[idx] = vh;
    WP[plane + idx] = (f16)((v - (float)vh) * LOSCALE);
}

// ---- conv: implicit GEMM, split-fp16 (denormal-safe), ky-group partials ----
// grid: (Coutp/16, 16 row-pairs, 2 ky-groups {0,1,2}/{3,4}). block 128 (2 waves).
// wave w computes output row h0+w; per-wave tile 16co x 64px, 1x4 frags 16x16x32.
// acc_h += Wh*Xh ; acc_m += Wh*Xls + Wls*Xh ; result = acc_h + acc_m/2048.
// (dropped Wl*Xl term is ~2^-22 relative — below fp32 accumulation noise)
__global__ __launch_bounds__(128) void conv_kernel(
    const f16* __restrict__ IN, int inPlane,
    const f16* __restrict__ WP, int wPlane,
    float* __restrict__ PART, int Cin, int Coutp,
    int cpg_out, int cpg_in, int limb)
{
    __shared__ __align__(16) f16 AL[2 * 5 * 16 * 40];  // [plane][kx][co 16][ci 32 pad40]
    __shared__ __align__(16) f16 BL[2 * 2 * 68 * 40];  // [plane][slab][px slot 68][ci pad40]
    const int mt = blockIdx.x, rp = blockIdx.y, zg = blockIdx.z;
    const int t = threadIdx.x;
    const int wave = t >> 6, lane = t & 63, l15 = lane & 15, quad = lane >> 4;
    const int h0 = rp * 2;
    const int co0 = mt * 16;
    const int g_max = (co0 + 15) / cpg_out;
    const int kylo = zg ? 3 : 0, kyhi = zg ? 4 : 2;

    f32x4 acc_h[4], acc_m[4];
#pragma unroll
    for (int j = 0; j < 4; j++) {
        acc_h[j] = (f32x4){0.f, 0.f, 0.f, 0.f};
        acc_m[j] = (f32x4){0.f, 0.f, 0.f, 0.f};
    }

    for (int ky = kylo; ky <= kyhi; ky++) {
        const int r0 = h0 + ky - 2;        // input row for wave 0
        int cnt[5];
#pragma unroll
        for (int kx = 0; kx < 5; kx++) {
            int c = (g_max + limb - (ky + kx) + 1) * cpg_in;
            c = c < Cin ? c : Cin;
            cnt[kx] = c > 0 ? c : 0;
        }
        const int cimax = cnt[0];

        for (int ci0 = 0; ci0 < cimax; ci0 += 32) {
            __syncthreads();   // protect previous iteration's LDS reads
            // stage B: 2 planes x 2 rows x 68 slots x 32 ci  (1088 float4)
#pragma unroll
            for (int i = 0; i < 9; i++) {
                int idx = t + i * 128;
                if (idx < 1088) {
                    int plane = idx >= 544 ? 1 : 0;
                    int rem2 = idx - plane * 544;
                    int slab = rem2 >= 272 ? 1 : 0;
                    int rem = rem2 - slab * 272;
                    int slot = rem >> 2;
                    int c8 = (rem & 3) * 8;
                    int r = r0 + slab;
                    int ip = slot - 2;
                    float4 v = make_float4(0.f, 0.f, 0.f, 0.f);
                    if (r >= 0 && r < HH && ip >= 0 && ip < WW)
                        v = *(const float4*)&IN[plane * inPlane + (r * WW + ip) * Cin + ci0 + c8];
                    *(float4*)&BL[((plane * 2 + slab) * 68 + slot) * 40 + c8] = v;
                }
            }
            // stage A: per live kx, 2 planes x 16co x 32ci = 128 float4 (1 pass)
            for (int kx = 0; kx < 5; kx++) {
                if (ci0 >= cnt[kx]) continue;
                int plane = t >> 6;
                int rem = t & 63;
                int co = rem >> 2;
                int c8 = (rem & 3) * 8;
                float4 v = *(const float4*)&WP[(size_t)plane * wPlane +
                            ((ky * 5 + kx) * Coutp + co0 + co) * Cin + ci0 + c8];
                *(float4*)&AL[((plane * 5 + kx) * 16 + co) * 40 + c8] = v;
            }
            __syncthreads();
            // compute
            for (int kx = 0; kx < 5; kx++) {
                if (ci0 >= cnt[kx]) continue;
                f16x8 ah = *(const f16x8*)&AL[((0 * 5 + kx) * 16 + l15) * 40 + quad * 8];
                f16x8 al = *(const f16x8*)&AL[((1 * 5 + kx) * 16 + l15) * 40 + quad * 8];
                f16x8 bh[4], bl[4];
#pragma unroll
                for (int j = 0; j < 4; j++) {
                    bh[j] = *(const f16x8*)&BL[((0 + wave) * 68 + j * 16 + l15 + kx) * 40 + quad * 8];
                    bl[j] = *(const f16x8*)&BL[((2 + wave) * 68 + j * 16 + l15 + kx) * 40 + quad * 8];
                }
#pragma unroll
                for (int j = 0; j < 4; j++) {
                    acc_h[j] = __builtin_amdgcn_mfma_f32_16x16x32_f16(ah, bh[j], acc_h[j], 0, 0, 0);
                    acc_m[j] = __builtin_amdgcn_mfma_f32_16x16x32_f16(ah, bl[j], acc_m[j], 0, 0, 0);
                    acc_m[j] = __builtin_amdgcn_mfma_f32_16x16x32_f16(al, bh[j], acc_m[j], 0, 0, 0);
                }
            }
        }
    }

    // store fp32 partials: PART[zg][co][px]
    const int h = h0 + wave;
    float* Pp = PART + (size_t)zg * Coutp * NPX;
#pragma unroll
    for (int j = 0; j < 4; j++) {
#pragma unroll
        for (int r = 0; r < 4; r++) {
            int co = co0 + quad * 4 + r;
            Pp[co * NPX + h * WW + j * 16 + l15] = acc_h[j][r] + acc_m[j][r] * INV_LOSCALE;
        }
    }
}

// ---- epilogue: sum 2 ky-group partials + bias + relu (+res) -> split-fp16 NHWC
__global__ __launch_bounds__(256) void epi_kernel(
    const float* __restrict__ PART, const float* __restrict__ bias,
    const f16* __restrict__ RES, int resPlane,
    f16* __restrict__ ACT, int actPlane, int Coutp)
{
    __shared__ __align__(16) float tile[64 * 65];
    const int h = blockIdx.x, cb = blockIdx.y;
    const int t = threadIdx.x;
    const int px = t & 63, cq = t >> 6;
    const size_t zstride = (size_t)Coutp * NPX;
#pragma unroll 4
    for (int cc = 0; cc < 16; cc++) {
        int co_l = cq * 16 + cc;
        int co = cb * 64 + co_l;
        size_t o = (size_t)co * NPX + h * WW + px;
        float s = bias[co] + PART[o] + PART[zstride + o];
        s = fmaxf(s, 0.f);
        tile[px * 65 + co_l] = s;
    }
    __syncthreads();
#pragma unroll 4
    for (int it = 0; it < 16; it++) {
        int lin = it * 256 + t;
        int co_l = lin & 63, px2 = lin >> 6;
        size_t o = (size_t)(h * WW + px2) * Coutp + cb * 64 + co_l;
        float v = tile[px2 * 65 + co_l];
        if (RES) v += (float)RES[o] + (float)RES[resPlane + o] * INV_LOSCALE;
        f16 vh = (f16)v;
        ACT[o] = vh;
        ACT[actPlane + o] = (f16)((v - (float)vh) * LOSCALE);
    }
}

// ---- final: sum 2 partials for mu/sig, bias, softplus, erf table ----
__global__ void final_kernel(const float* __restrict__ PART,
                             const float* __restrict__ b_out,
                             float* __restrict__ OUT) {
    int g = blockIdx.y;
    int px = blockIdx.x * 256 + threadIdx.x;
    float mu = b_out[3 * g + 1];
    float s  = b_out[3 * g + 2];
#pragma unroll
    for (int zg = 0; zg < 2; zg++) {
        mu += PART[(size_t)zg * 128 * NPX + (2 * g) * NPX + px];
        s  += PART[(size_t)zg * 128 * NPX + (2 * g + 1) * NPX + px];
    }
    float sp  = fmaxf(s, 0.f) + log1pf(expf(-fabsf(s)));
    float sig = sp + 1e-6f;
    float inv = 1.f / (sig * 1.41421356237f);
#pragma unroll
    for (int k = 0; k < 8; k++) {
        float z = ((float)k - 3.0f - mu) * inv;
        OUT[((size_t)g * NPX + px) * 8 + k] = 32768.f * (1.f + erff(z));
    }
}

extern "C" void kernel_launch(void* const* d_in, const int* in_sizes, int n_in,
                              void* d_out, int out_size, void* d_ws, size_t ws_size,
                              hipStream_t stream) {
    const float* data  = (const float*)d_in[0];
    const float* mask  = (const float*)d_in[1];
    const float* w_in  = (const float*)d_in[2];
    const float* b_in  = (const float*)d_in[3];
    const float* w_hid = (const float*)d_in[4];
    const float* b_hid = (const float*)d_in[5];
    const float* w_out = (const float*)d_in[6];
    const float* b_out = (const float*)d_in[7];
    float* out = (float*)d_out;

    // workspace: 6.55 + 2 + 2 + 4.2 = 14.25 MB total
    f16* WP = (f16*)d_ws;                    // 2 planes x 25*256*256 f16
    f16* P  = WP + 2 * 1638400;              // 2 planes x 524288 f16
    f16* Q  = P + 2 * 524288;                // 2 planes x 524288 f16
    float* PART = (float*)(Q + 2 * 524288);  // 2 x 256*2048 fp32
    f16* X0 = Q;                             // alias: X0 dead before Q first written

    prep_kernel<<<512, 256, 0, stream>>>(data, mask, X0, NPX * 64);

    // input conv: Cin=64, Coutp=256, strict (limb=3), cpg_in=1
    repack_kernel<<<1600, 256, 0, stream>>>(w_in, WP, 6, 8, 0, 3, 0);
    conv_kernel<<<dim3(16, 16, 2), 128, 0, stream>>>(X0, NPX * 64, WP, 25 * 256 * 64,
                                                     PART, 64, 256, 4, 1, 3);
    epi_kernel<<<dim3(32, 4), 256, 0, stream>>>(PART, b_in, nullptr, 0, P, 524288, 256);

    f16* x = P; f16* h = Q;
    for (int i = 0; i < 5; i++) {
        const float* w1 = w_hid + (size_t)(2 * i) * 256 * 256 * 25;
        const float* w2 = w_hid + (size_t)(2 * i + 1) * 256 * 256 * 25;
        repack_kernel<<<6400, 256, 0, stream>>>(w1, WP, 8, 8, 2, 4, 0);
        conv_kernel<<<dim3(16, 16, 2), 128, 0, stream>>>(x, 524288, WP, 25 * 256 * 256,
                                                         PART, 256, 256, 4, 4, 4);
        epi_kernel<<<dim3(32, 4), 256, 0, stream>>>(PART, b_hid + 2 * i * 256,
                                                    nullptr, 0, h, 524288, 256);
        repack_kernel<<<6400, 256, 0, stream>>>(w2, WP, 8, 8, 2, 4, 0);
        conv_kernel<<<dim3(16, 16, 2), 128, 0, stream>>>(h, 524288, WP, 25 * 256 * 256,
                                                         PART, 256, 256, 4, 4, 4);
        epi_kernel<<<dim3(32, 4), 256, 0, stream>>>(PART, b_hid + (2 * i + 1) * 256,
                                                    x, 524288, h, 524288, 256);
        f16* tmp = x; x = h; h = tmp;
    }

    // output conv: only mu/sig channels -> Coutp=128, cpg_out=2, limb=4
    repack_kernel<<<3200, 256, 0, stream>>>(w_out, WP, 8, 7, 2, 4, 1);
    conv_kernel<<<dim3(8, 16, 2), 128, 0, stream>>>(x, 524288, WP, 25 * 128 * 256,
                                                    PART, 256, 128, 2, 4, 4);
    final_kernel<<<dim3(8, 64), 256, 0, stream>>>(PART, b_out, out);
}

// Round 6
// 632.118 us; speedup vs baseline: 7.0570x; 1.8893x over previous
//
#include <hip/hip_runtime.h>
#include <math.h>

typedef _Float16 f16;
typedef _Float16 f16x8 __attribute__((ext_vector_type(8)));
typedef float f32x4 __attribute__((ext_vector_type(4)));

#define HH 32
#define WW 64
#define NPX 2048
#define SLOTS 68          // 64 px + 2 halo each side
#define RROWS 36          // 32 rows + 2 halo each side
// lo-planes pre-scaled by 2^11 to stay in fp16 NORMAL range (denormal inputs
// are flushed by the MFMA pipe -- proven by rounds 2/4 bit-identical failure)
#define LOSCALE 2048.0f
#define INV_LOSCALE 4.8828125e-4f

typedef const __attribute__((address_space(1))) void gvoid;
typedef __attribute__((address_space(3))) void lvoid;
__device__ __forceinline__ void gload_lds16(const void* g, void* l) {
    __builtin_amdgcn_global_load_lds((gvoid*)g, (lvoid*)l, 16, 0, 0);
}

// ---- zero halo act buffers (P|Q|X0 contiguous in ws; re-poisoned every call)
__global__ void zero_kernel(f16* p, int n8) {
    int i = blockIdx.x * 256 + threadIdx.x;
    if (i < n8) *(int4*)(p + i * 8) = make_int4(0, 0, 0, 0);
}

// ---- prep: X0 halo buffer [row][slot][ci=64], hi=(data-3.5)*mask (exact), lo=0
__global__ void prep_kernel(const float* __restrict__ data,
                            const float* __restrict__ mask,
                            f16* __restrict__ X0, int plane) {
    int idx = blockIdx.x * 256 + threadIdx.x;      // px*64 + ci
    if (idx >= NPX * 64) return;
    int px = idx >> 6, ci = idx & 63;
    int hh = px >> 6, w = px & 63;
    float v = (data[ci * NPX + px] - 3.5f) * mask[ci * NPX + px];
    int dst = ((hh + 2) * SLOTS + (w + 2)) * 64 + ci;
    X0[dst] = (f16)v;
    X0[plane + dst] = (f16)0.f;
}

// ---- repack: WP[0][tap][co_p][ci]=fp16(w_masked); WP[1]=fp16((w-hi)*2048)
// is_out: co_p = g*2+c -> orig co = g*3+1+c (mu,sig only; logits provably unused)
__global__ void repack_kernel(const float* __restrict__ W, f16* __restrict__ WP,
                              int cin_log2, int coutp_log2,
                              int cpg_in_log2, int limb, int is_out) {
    int idx = blockIdx.x * 256 + threadIdx.x;
    int Cin = 1 << cin_log2;
    int plane = 25 << (cin_log2 + coutp_log2);
    int ci = idx & (Cin - 1);
    int rest = idx >> cin_log2;
    int co_p = rest & ((1 << coutp_log2) - 1);
    int tap = rest >> coutp_log2;
    if (tap >= 25) return;
    int ky = tap / 5, kx = tap - 5 * ky;
    int co_orig, g_out;
    if (is_out) { g_out = co_p >> 1; co_orig = 3 * g_out + 1 + (co_p & 1); }
    else        { g_out = co_p >> 2; co_orig = co_p; }
    int g_in = ci >> cpg_in_log2;
    float v = 0.f;
    if (ky + kx <= limb + g_out - g_in)
        v = W[(co_orig * Cin + ci) * 25 + tap];
    f16 vh = (f16)v;
    WP[idx] = vh;
    WP[plane + idx] = (f16)((v - (float)vh) * LOSCALE);
}

// ---- fused conv: implicit GEMM, split-fp16, ky-per-wave, in-kernel reduction
// grid (Coutp/32, 32 rows), block 320 = 5 waves; wave kw handles tap-row ky=kw.
// Per-wave tile 32co x 64px via 2x4 frags of mfma_f32_16x16x32_f16.
// B (acts, halo layout) -> LDS via global_load_lds; A (weights) global->VGPR.
// Epilogue fused: bias+relu(+res)+split-f16 store (mode0) or erf table (mode1).
__global__ __launch_bounds__(320) void conv_kernel(
    const f16* __restrict__ IN, int Cin, int inPlane,
    const f16* __restrict__ WP, int wPlane,
    const float* __restrict__ bias,
    const f16* __restrict__ RES, int resPlane,
    f16* __restrict__ OA, int oaPlane,
    float* __restrict__ OT,
    int Coutp, int cpg_out, int cpg_in, int limb, int mode)
{
    __shared__ __align__(16) char SMEM[46080];
    f16* BL = (f16*)SMEM;      // [plane2][row5][slot68][ci32] = 21760 f16 (+pad)
    float* RED = (float*)SMEM; // [kw5][px64][co pad36] = 11520 f32 (after K loop)

    const int t = threadIdx.x;
    const int kw = t >> 6;                 // wave index == ky
    const int lane = t & 63, l15 = lane & 15, q = lane >> 4;
    const int mt = blockIdx.x, h = blockIdx.y;
    const int co0 = mt * 32;
    const int g_max = (co0 + 31) / cpg_out;

    // masked K-extent per kx for this wave's ky (tap allowed iff ky+kx<=limb+g_out-g_in)
    int cnt[5];
#pragma unroll
    for (int kx = 0; kx < 5; kx++) {
        int c = (g_max + limb - (kw + kx) + 1) * cpg_in;
        c = c < Cin ? c : Cin;
        cnt[kx] = c > 0 ? c : 0;
    }
    int ci_top = (g_max + limb + 1) * cpg_in;   // block-uniform chunk bound
    ci_top = ci_top < Cin ? ci_top : Cin;

    // per-lane staging sources: 2720 16B-units = [plane][row5][slot68][ci32]
    const f16* src[9];
#pragma unroll
    for (int r = 0; r < 9; r++) {
        int u = r * 320 + t;
        if (u >= 2720) u = 0;              // tail lanes: any valid addr (dest=pad)
        int plane = u / 1360;
        int rem = u - plane * 1360;
        int s4 = rem >> 2;
        int ci16 = rem & 3;
        int row = s4 / 68;
        int slot = s4 - row * 68;
        src[r] = IN + plane * inPlane + ((h + row) * SLOTS + slot) * Cin + ci16 * 8;
    }

    f32x4 acc_h[2][4], acc_m[2][4];
#pragma unroll
    for (int i = 0; i < 2; i++)
#pragma unroll
        for (int j = 0; j < 4; j++) {
            acc_h[i][j] = (f32x4){0.f, 0.f, 0.f, 0.f};
            acc_m[i][j] = (f32x4){0.f, 0.f, 0.f, 0.f};
        }

    for (int ci0 = 0; ci0 < ci_top; ci0 += 32) {
        __syncthreads();
        // stage B: 43520 B = 9 rounds x 5 waves x 1024 B, direct global->LDS
#pragma unroll
        for (int r = 0; r < 9; r++) {
            int ub = r * 320 + kw * 64;
            if (ub < 2720)                 // wave-uniform (BL padded for overshoot)
                gload_lds16(src[r] + ci0, BL + ub * 8);
        }
        __syncthreads();

#pragma unroll
        for (int kx = 0; kx < 5; kx++) {
            if (ci0 >= cnt[kx]) continue;  // wave-uniform
            // A frags straight from global (L2-resident weights)
            const f16* wp = WP + ((size_t)(kw * 5 + kx) * Coutp + co0) * Cin + ci0;
            f16x8 ah0 = *(const f16x8*)(wp + l15 * Cin + q * 8);
            f16x8 ah1 = *(const f16x8*)(wp + (16 + l15) * Cin + q * 8);
            f16x8 al0 = *(const f16x8*)(wp + wPlane + l15 * Cin + q * 8);
            f16x8 al1 = *(const f16x8*)(wp + wPlane + (16 + l15) * Cin + q * 8);
            // B frags from LDS (stride 32 f16 = bank-even for b128)
            f16x8 bh[4], bl[4];
#pragma unroll
            for (int j = 0; j < 4; j++) {
                int slot = j * 16 + l15 + kx;
                bh[j] = *(const f16x8*)&BL[(0 * 5 + kw) * (SLOTS * 32) + slot * 32 + q * 8];
                bl[j] = *(const f16x8*)&BL[(1 * 5 + kw) * (SLOTS * 32) + slot * 32 + q * 8];
            }
#pragma unroll
            for (int j = 0; j < 4; j++) {
                acc_h[0][j] = __builtin_amdgcn_mfma_f32_16x16x32_f16(ah0, bh[j], acc_h[0][j], 0, 0, 0);
                acc_h[1][j] = __builtin_amdgcn_mfma_f32_16x16x32_f16(ah1, bh[j], acc_h[1][j], 0, 0, 0);
                acc_m[0][j] = __builtin_amdgcn_mfma_f32_16x16x32_f16(ah0, bl[j], acc_m[0][j], 0, 0, 0);
                acc_m[0][j] = __builtin_amdgcn_mfma_f32_16x16x32_f16(al0, bh[j], acc_m[0][j], 0, 0, 0);
                acc_m[1][j] = __builtin_amdgcn_mfma_f32_16x16x32_f16(ah1, bl[j], acc_m[1][j], 0, 0, 0);
                acc_m[1][j] = __builtin_amdgcn_mfma_f32_16x16x32_f16(al1, bh[j], acc_m[1][j], 0, 0, 0);
            }
        }
    }

    // in-block ky reduction through LDS (C/D layout: px=l15, co=quad*4+r)
    __syncthreads();   // all BL reads done before RED aliases SMEM
#pragma unroll
    for (int i = 0; i < 2; i++)
#pragma unroll
        for (int j = 0; j < 4; j++) {
            f32x4 v;
#pragma unroll
            for (int r = 0; r < 4; r++)
                v[r] = acc_h[i][j][r] + acc_m[i][j][r] * INV_LOSCALE;
            *(f32x4*)&RED[(kw * 64 + j * 16 + l15) * 36 + i * 16 + q * 4] = v;
        }
    __syncthreads();

    if (mode == 0) {
        // bias + relu (+ residual) -> split-f16 halo store (C=256 layout)
        for (int c = t; c < 2048; c += 320) {
            int px = c >> 5, col = c & 31;
            float v = bias[co0 + col];
#pragma unroll
            for (int k5 = 0; k5 < 5; k5++) v += RED[(k5 * 64 + px) * 36 + col];
            v = fmaxf(v, 0.f);
            int idx = ((h + 2) * SLOTS + px + 2) * 256 + co0 + col;
            if (RES) v += (float)RES[idx] + (float)RES[resPlane + idx] * INV_LOSCALE;
            f16 vh = (f16)v;
            OA[idx] = vh;
            OA[oaPlane + idx] = (f16)((v - (float)vh) * LOSCALE);
        }
    } else {
        // output conv: co_p = g*2 + {mu,sig}; fold softplus+erf table here
        for (int c = t; c < 2048; c += 320) {
            int px = c >> 5, col = c & 31;
            int co = co0 + col;
            float v = bias[3 * (co >> 1) + 1 + (co & 1)];
#pragma unroll
            for (int k5 = 0; k5 < 5; k5++) v += RED[(k5 * 64 + px) * 36 + col];
            RED[px * 36 + col] = v;    // own-cell write after own-cell reads: safe
        }
        __syncthreads();
        for (int c = t; c < 1024; c += 320) {
            int px = c & 63, gl = c >> 6;
            float mu = RED[px * 36 + 2 * gl];
            float s  = RED[px * 36 + 2 * gl + 1];
            float sp = fmaxf(s, 0.f) + log1pf(expf(-fabsf(s)));
            float sig = sp + 1e-6f;
            float inv = 1.f / (sig * 1.41421356237f);
            int g = (co0 >> 1) + gl;
            float* o = OT + ((size_t)g * NPX + h * WW + px) * 8;
#pragma unroll
            for (int k = 0; k < 8; k++) {
                float z = ((float)k - 3.0f - mu) * inv;
                o[k] = 32768.f * (1.f + erff(z));
            }
        }
    }
}

extern "C" void kernel_launch(void* const* d_in, const int* in_sizes, int n_in,
                              void* d_out, int out_size, void* d_ws, size_t ws_size,
                              hipStream_t stream) {
    const float* data  = (const float*)d_in[0];
    const float* mask  = (const float*)d_in[1];
    const float* w_in  = (const float*)d_in[2];
    const float* b_in  = (const float*)d_in[3];
    const float* w_hid = (const float*)d_in[4];
    const float* b_hid = (const float*)d_in[5];
    const float* w_out = (const float*)d_in[6];
    const float* b_out = (const float*)d_in[7];
    float* out = (float*)d_out;

    // ws: WP 6.55MB | P 2.51 | Q 2.51 | X0 0.63  = 12.2 MB total
    f16* WP = (f16*)d_ws;                  // 2 x 25*256*256 f16
    f16* P  = WP + 3276800;                // 2 x 36*68*256 f16 (halo act, x)
    f16* Q  = P + 1253376;                 // 2 x 36*68*256 f16 (halo act, h1)
    f16* X0 = Q + 1253376;                 // 2 x 36*68*64 f16

    // zero P|Q|X0 (contiguous): 2,820,096 f16 = 352,512 x (8 f16)
    zero_kernel<<<1377, 256, 0, stream>>>(P, 352512);
    prep_kernel<<<512, 256, 0, stream>>>(data, mask, X0, 156672);

    // input conv: Cin=64, strict (limb=3), cpg_in=1 -> P
    repack_kernel<<<1600, 256, 0, stream>>>(w_in, WP, 6, 8, 0, 3, 0);
    conv_kernel<<<dim3(8, 32), 320, 0, stream>>>(X0, 64, 156672, WP, 409600,
        b_in, nullptr, 0, P, 626688, nullptr, 256, 4, 1, 3, 0);

    for (int i = 0; i < 5; i++) {
        repack_kernel<<<6400, 256, 0, stream>>>(w_hid + (size_t)(2 * i) * 1638400,
                                                WP, 8, 8, 2, 4, 0);
        conv_kernel<<<dim3(8, 32), 320, 0, stream>>>(P, 256, 626688, WP, 1638400,
            b_hid + 2 * i * 256, nullptr, 0, Q, 626688, nullptr, 256, 4, 4, 4, 0);
        repack_kernel<<<6400, 256, 0, stream>>>(w_hid + (size_t)(2 * i + 1) * 1638400,
                                                WP, 8, 8, 2, 4, 0);
        // conv2: residual x (P) added after relu, written back in-place to P
        conv_kernel<<<dim3(8, 32), 320, 0, stream>>>(Q, 256, 626688, WP, 1638400,
            b_hid + (2 * i + 1) * 256, P, 626688, P, 626688, nullptr, 256, 4, 4, 4, 0);
    }

    // output conv: mu/sig only (Coutp=128, cpg_out=2, limb=4) + fused erf table
    repack_kernel<<<3200, 256, 0, stream>>>(w_out, WP, 8, 7, 2, 4, 1);
    conv_kernel<<<dim3(4, 32), 320, 0, stream>>>(P, 256, 626688, WP, 819200,
        b_out, nullptr, 0, nullptr, 0, out, 128, 2, 4, 4, 1);
}

// Round 7
// 497.298 us; speedup vs baseline: 8.9702x; 1.2711x over previous
//
#include <hip/hip_runtime.h>
#include <math.h>

typedef _Float16 f16;
typedef _Float16 f16x8 __attribute__((ext_vector_type(8)));
typedef float f32x4 __attribute__((ext_vector_type(4)));

#define HH 32
#define WW 64
#define NPX 2048
#define SLOTS 68          // 64 px + 2 halo each side
// lo-planes pre-scaled by 2^11 to stay in fp16 NORMAL range (denormal inputs
// are flushed by the MFMA pipe -- proven by rounds 2/4 bit-identical failure)
#define LOSCALE 2048.0f
#define INV_LOSCALE 4.8828125e-4f

typedef const __attribute__((address_space(1))) void gvoid;
typedef __attribute__((address_space(3))) void lvoid;
__device__ __forceinline__ void gload_lds16(const void* g, void* l) {
    __builtin_amdgcn_global_load_lds((gvoid*)g, (lvoid*)l, 16, 0, 0);
}

// ---- zero halo act buffers (P|Q|X0 contiguous in ws; re-poisoned every call)
__global__ void zero_kernel(f16* p, int n8) {
    int i = blockIdx.x * 256 + threadIdx.x;
    if (i < n8) *(int4*)(p + i * 8) = make_int4(0, 0, 0, 0);
}

// ---- prep: X0 halo buffer [row][slot][ci=64], hi=(data-3.5)*mask (exact), lo=0
__global__ void prep_kernel(const float* __restrict__ data,
                            const float* __restrict__ mask,
                            f16* __restrict__ X0, int plane) {
    int idx = blockIdx.x * 256 + threadIdx.x;      // px*64 + ci
    if (idx >= NPX * 64) return;
    int px = idx >> 6, ci = idx & 63;
    int hh = px >> 6, w = px & 63;
    float v = (data[ci * NPX + px] - 3.5f) * mask[ci * NPX + px];
    int dst = ((hh + 2) * SLOTS + (w + 2)) * 64 + ci;
    X0[dst] = (f16)v;
    X0[plane + dst] = (f16)0.f;
}

// ---- repack: WP[0][tap][co_p][ci]=fp16(w_masked); WP[1]=fp16((w-hi)*2048)
// is_out: co_p = g*2+c -> orig co = g*3+1+c (mu,sig only; logits provably unused)
__global__ void repack_kernel(const float* __restrict__ W, f16* __restrict__ WP,
                              int cin_log2, int coutp_log2,
                              int cpg_in_log2, int limb, int is_out) {
    int idx = blockIdx.x * 256 + threadIdx.x;
    int Cin = 1 << cin_log2;
    int plane = 25 << (cin_log2 + coutp_log2);
    int ci = idx & (Cin - 1);
    int rest = idx >> cin_log2;
    int co_p = rest & ((1 << coutp_log2) - 1);
    int tap = rest >> coutp_log2;
    if (tap >= 25) return;
    int ky = tap / 5, kx = tap - 5 * ky;
    int co_orig, g_out;
    if (is_out) { g_out = co_p >> 1; co_orig = 3 * g_out + 1 + (co_p & 1); }
    else        { g_out = co_p >> 2; co_orig = co_p; }
    int g_in = ci >> cpg_in_log2;
    float v = 0.f;
    if (ky + kx <= limb + g_out - g_in)
        v = W[(co_orig * Cin + ci) * 25 + tap];
    f16 vh = (f16)v;
    WP[idx] = vh;
    WP[plane + idx] = (f16)((v - (float)vh) * LOSCALE);
}

// ---- fused conv: implicit GEMM, split-fp16, ky-per-wave, in-kernel reduction
// grid = nmt*32 blocks (2 blocks/CU); in-kernel complementary-mt pairing:
// block b and b+nmt*16 land on the same CU (round-robin) and get mt / nmt-1-mt
// whose K-chunk counts sum to a near-constant -> balanced + latency overlap.
// Block 320 thr = 5 waves; wave kw handles tap-row ky=kw; per-wave tile
// 16co x 64px via 1x4 frags of mfma_f32_16x16x32_f16, depth-1 A prefetch.
__global__ __launch_bounds__(320, 3) void conv_kernel(
    const f16* __restrict__ IN, int Cin, int inPlane,
    const f16* __restrict__ WP, int wPlane,
    const float* __restrict__ bias,
    const f16* __restrict__ RES, int resPlane,
    f16* __restrict__ OA, int oaPlane,
    float* __restrict__ OT,
    int nmt, int Coutp, int cpg_out, int cpg_in, int limb, int mode)
{
    __shared__ __align__(16) char SMEM[46080];
    f16* BL = (f16*)SMEM;      // [plane2][row5][slot68][ci32] = 43520 B (+pad)
    float* RED = (float*)SMEM; // [kw5][px64][co pad20] = 25600 B (after K loop)

    const int t = threadIdx.x;
    const int kw = t >> 6;                 // wave index == ky
    const int lane = t & 63, l15 = lane & 15, q = lane >> 4;

    // balanced mapping
    int b = blockIdx.x;
    int half = nmt << 4;
    int slot = b >= half ? 1 : 0;
    int idx = b - (slot ? half : 0);
    int mt8 = idx >> 5;
    const int h = idx & 31;
    const int mt = slot ? (nmt - 1 - mt8) : mt8;
    const int co0 = mt * 16;
    const int g_max = (co0 + 15) / cpg_out;

    // masked K-extent per kx for this wave's ky (allowed iff ky+kx<=limb+g_out-g_in)
    int cnt[5];
#pragma unroll
    for (int kx = 0; kx < 5; kx++) {
        int c = (g_max + limb - (kw + kx) + 1) * cpg_in;
        c = c < Cin ? c : Cin;
        cnt[kx] = c > 0 ? c : 0;
    }
    int ci_top = (g_max + limb + 1) * cpg_in;   // block-uniform chunk bound
    ci_top = ci_top < Cin ? ci_top : Cin;

    // per-lane staging sources: 2720 16B-units = [plane][row5][slot68][ci32]
    const f16* src[9];
#pragma unroll
    for (int r = 0; r < 9; r++) {
        int u = r * 320 + t;
        if (u >= 2720) u = 0;              // tail lanes: any valid addr (dest=pad)
        int plane = u / 1360;
        int rem = u - plane * 1360;
        int s4 = rem >> 2;
        int ci16 = rem & 3;
        int row = s4 / 68;
        int slt = s4 - row * 68;
        src[r] = IN + plane * inPlane + ((h + row) * SLOTS + slt) * Cin + ci16 * 8;
    }

    f32x4 acc_h[4], acc_m[4];
#pragma unroll
    for (int j = 0; j < 4; j++) {
        acc_h[j] = (f32x4){0.f, 0.f, 0.f, 0.f};
        acc_m[j] = (f32x4){0.f, 0.f, 0.f, 0.f};
    }

    const size_t kxs = (size_t)Coutp * Cin;

    for (int ci0 = 0; ci0 < ci_top; ci0 += 32) {
        __syncthreads();
        // stage B: 43520 B = 9 rounds x 5 waves x 1024 B, direct global->LDS
#pragma unroll
        for (int r = 0; r < 9; r++) {
            int ub = r * 320 + kw * 64;
            if (ub < 2720)                 // wave-uniform (BL padded for overshoot)
                gload_lds16(src[r] + ci0, BL + ub * 8);
        }
        __syncthreads();

        // A frags straight from global (L2-resident), depth-1 prefetch over kx
        const f16* wbase = WP + ((size_t)(kw * 5) * Coutp + co0) * Cin + ci0;
        f16x8 cah, cal, nah, nal;
        if (ci0 < cnt[0]) {
            cah = *(const f16x8*)(wbase + l15 * Cin + q * 8);
            cal = *(const f16x8*)(wbase + wPlane + l15 * Cin + q * 8);
        }
#pragma unroll
        for (int kx = 0; kx < 5; kx++) {
            if (ci0 >= cnt[kx]) break;     // cnt non-increasing in kx, wave-uniform
            if (kx < 4 && ci0 < cnt[kx + 1]) {
                nah = *(const f16x8*)(wbase + (kx + 1) * kxs + l15 * Cin + q * 8);
                nal = *(const f16x8*)(wbase + (kx + 1) * kxs + wPlane + l15 * Cin + q * 8);
            }
            f16x8 bh[4], bl[4];
#pragma unroll
            for (int j = 0; j < 4; j++) {
                int slt = j * 16 + l15 + kx;
                bh[j] = *(const f16x8*)&BL[(0 * 5 + kw) * (SLOTS * 32) + slt * 32 + q * 8];
                bl[j] = *(const f16x8*)&BL[(1 * 5 + kw) * (SLOTS * 32) + slt * 32 + q * 8];
            }
#pragma unroll
            for (int j = 0; j < 4; j++) {
                acc_h[j] = __builtin_amdgcn_mfma_f32_16x16x32_f16(cah, bh[j], acc_h[j], 0, 0, 0);
                acc_m[j] = __builtin_amdgcn_mfma_f32_16x16x32_f16(cah, bl[j], acc_m[j], 0, 0, 0);
                acc_m[j] = __builtin_amdgcn_mfma_f32_16x16x32_f16(cal, bh[j], acc_m[j], 0, 0, 0);
            }
            cah = nah; cal = nal;
        }
    }

    // in-block ky reduction through LDS (C/D layout: px=j*16+l15, co=q*4+r)
    __syncthreads();   // all BL reads done before RED aliases SMEM
#pragma unroll
    for (int j = 0; j < 4; j++) {
        f32x4 v;
#pragma unroll
        for (int r = 0; r < 4; r++)
            v[r] = acc_h[j][r] + acc_m[j][r] * INV_LOSCALE;
        *(f32x4*)&RED[(kw * 64 + j * 16 + l15) * 20 + q * 4] = v;
    }
    __syncthreads();

    if (mode == 0) {
        // bias + relu (+ residual) -> split-f16 halo store (C=Coutp layout)
        for (int c = t; c < 1024; c += 320) {
            int px = c >> 4, col = c & 15;
            float v = bias[co0 + col];
#pragma unroll
            for (int k5 = 0; k5 < 5; k5++) v += RED[(k5 * 64 + px) * 20 + col];
            v = fmaxf(v, 0.f);
            int o = ((h + 2) * SLOTS + px + 2) * Coutp + co0 + col;
            if (RES) v += (float)RES[o] + (float)RES[resPlane + o] * INV_LOSCALE;
            f16 vh = (f16)v;
            OA[o] = vh;
            OA[oaPlane + o] = (f16)((v - (float)vh) * LOSCALE);
        }
    } else {
        // output conv: co_p = g*2 + {mu,sig}; fold bias+softplus+erf table here
        for (int c = t; c < 1024; c += 320) {
            int px = c >> 4, col = c & 15;
            float v = bias[3 * ((co0 + col) >> 1) + 1 + (col & 1)];
#pragma unroll
            for (int k5 = 0; k5 < 5; k5++) v += RED[(k5 * 64 + px) * 20 + col];
            RED[px * 20 + col] = v;    // own-cell write after own-cell reads: safe
        }
        __syncthreads();
        for (int c = t; c < 512; c += 320) {
            int px = c >> 3, gl = c & 7;
            float mu = RED[px * 20 + 2 * gl];
            float s  = RED[px * 20 + 2 * gl + 1];
            float sp = fmaxf(s, 0.f) + log1pf(expf(-fabsf(s)));
            float sig = sp + 1e-6f;
            float inv = 1.f / (sig * 1.41421356237f);
            int g = (co0 >> 1) + gl;
            float* o = OT + ((size_t)g * NPX + h * WW + px) * 8;
#pragma unroll
            for (int k = 0; k < 8; k++) {
                float z = ((float)k - 3.0f - mu) * inv;
                o[k] = 32768.f * (1.f + erff(z));
            }
        }
    }
}

extern "C" void kernel_launch(void* const* d_in, const int* in_sizes, int n_in,
                              void* d_out, int out_size, void* d_ws, size_t ws_size,
                              hipStream_t stream) {
    const float* data  = (const float*)d_in[0];
    const float* mask  = (const float*)d_in[1];
    const float* w_in  = (const float*)d_in[2];
    const float* b_in  = (const float*)d_in[3];
    const float* w_hid = (const float*)d_in[4];
    const float* b_hid = (const float*)d_in[5];
    const float* w_out = (const float*)d_in[6];
    const float* b_out = (const float*)d_in[7];
    float* out = (float*)d_out;

    // ws: WP 6.55MB | P 2.51 | Q 2.51 | X0 0.63  = 12.2 MB total
    f16* WP = (f16*)d_ws;                  // 2 x 25*256*256 f16
    f16* P  = WP + 3276800;                // 2 x 36*68*256 f16 (halo act, x)
    f16* Q  = P + 1253376;                 // 2 x 36*68*256 f16 (halo act, h1)
    f16* X0 = Q + 1253376;                 // 2 x 36*68*64 f16

    // zero P|Q|X0 (contiguous): 2,820,096 f16 = 352,512 x (8 f16)
    zero_kernel<<<1377, 256, 0, stream>>>(P, 352512);
    prep_kernel<<<512, 256, 0, stream>>>(data, mask, X0, 156672);

    // input conv: Cin=64, strict (limb=3), cpg_in=1 -> P
    repack_kernel<<<1600, 256, 0, stream>>>(w_in, WP, 6, 8, 0, 3, 0);
    conv_kernel<<<512, 320, 0, stream>>>(X0, 64, 156672, WP, 409600,
        b_in, nullptr, 0, P, 626688, nullptr, 16, 256, 4, 1, 3, 0);

    for (int i = 0; i < 5; i++) {
        repack_kernel<<<6400, 256, 0, stream>>>(w_hid + (size_t)(2 * i) * 1638400,
                                                WP, 8, 8, 2, 4, 0);
        conv_kernel<<<512, 320, 0, stream>>>(P, 256, 626688, WP, 1638400,
            b_hid + 2 * i * 256, nullptr, 0, Q, 626688, nullptr, 16, 256, 4, 4, 4, 0);
        repack_kernel<<<6400, 256, 0, stream>>>(w_hid + (size_t)(2 * i + 1) * 1638400,
                                                WP, 8, 8, 2, 4, 0);
        // conv2: residual x (P) added after relu, written back in-place to P
        conv_kernel<<<512, 320, 0, stream>>>(Q, 256, 626688, WP, 1638400,
            b_hid + (2 * i + 1) * 256, P, 626688, P, 626688, nullptr, 16, 256, 4, 4, 4, 0);
    }

    // output conv: mu/sig only (Coutp=128, cpg_out=2, limb=4) + fused erf table
    repack_kernel<<<3200, 256, 0, stream>>>(w_out, WP, 8, 7, 2, 4, 1);
    conv_kernel<<<256, 320, 0, stream>>>(P, 256, 626688, WP, 819200,
        b_out, nullptr, 0, nullptr, 0, out, 8, 128, 2, 4, 4, 1);
}